// Round 2
// baseline (1202.822 us; speedup 1.0000x reference)
//
#include <hip/hip_runtime.h>
#include <hip/hip_bf16.h>

// NegSamplerMiniBatch: out[n] = centroids[ idx of 2nd-largest distance(x_n,c_k) ]
// N=262144, D=256, K=256, f32.
//
// Rank key: s_k = |c_k|^2 - 2 x.c_k (monotone in distance). Dot via split-bf16
// MFMA: x = xh + xl, c = ch + cl (truncation splits); dot ~= xh.ch + xl.ch +
// xh.cl, f32 accumulate. Rows with top-3 gap < EPS=0.02 exactly re-ranked in
// f64 by refine_kernel.
//
// Pipeline (m97-style): LDS double-buffered; iteration k issues the C DMA
// (global_load_lds, frag-order global layout -> linear LDS) and the X
// split+write for chunk k+1 into buf^1 BEFORE the 48-MFMA cluster on buf,
// then a single __syncthreads (implicit vmcnt(0)) per chunk. DMA latency
// hides under the MFMA cluster instead of being serially exposed.

typedef __attribute__((ext_vector_type(8))) __bf16 bf16x8;
typedef __attribute__((ext_vector_type(4))) float f32x4;
typedef __attribute__((ext_vector_type(8))) unsigned short u16x8;

#define EPS 0.02f
#define CAP_MAX 65536

__device__ __forceinline__ void split_f32(float v, unsigned short& hi, unsigned short& lo) {
    unsigned u = __float_as_uint(v);
    hi = (unsigned short)(u >> 16);                      // truncate to bf16
    float hif = __uint_as_float(u & 0xFFFF0000u);
    float lov = v - hif;                                 // exact residual
    lo = (unsigned short)(__float_as_uint(lov) >> 16);
}

__device__ __forceinline__ unsigned f32_key(float s) {   // order-preserving u32
    unsigned u = __float_as_uint(s);
    return u ^ ((unsigned)((int)u >> 31) | 0x80000000u);
}
__device__ __forceinline__ float key_to_float(unsigned key) {
    unsigned k = key & 0xFFFFFF00u;
    unsigned u = (k & 0x80000000u) ? (k ^ 0x80000000u) : ~k;
    return __uint_as_float(u);
}

__device__ __forceinline__ void ins3(unsigned& k1, unsigned& k2, unsigned& k3, unsigned v) {
    if (v > k1)      { k3 = k2; k2 = k1; k1 = v; }
    else if (v > k2) { k3 = k2; k2 = v; }
    else if (v > k3) { k3 = v; }
}

__device__ __forceinline__ void gload16(const unsigned short* g, unsigned short* l) {
    __builtin_amdgcn_global_load_lds(
        (const __attribute__((address_space(1))) void*)g,
        (__attribute__((address_space(3))) void*)l, 16, 0, 0);
}

// -------- one-time: C -> bf16 hi/lo in frag-order layout, plus c2 --------
__global__ __launch_bounds__(64) void cvt_kernel(const float* __restrict__ C,
    float* __restrict__ c2f, double* __restrict__ c2d,
    unsigned short* __restrict__ CHg, unsigned short* __restrict__ CLg) {
    const int k = blockIdx.x, l = threadIdx.x;
    float4 v = ((const float4*)(C + (size_t)k * 256))[l];
    unsigned short h0,h1,h2,h3, l0,l1,l2,l3;
    split_f32(v.x,h0,l0); split_f32(v.y,h1,l1); split_f32(v.z,h2,l2); split_f32(v.w,h3,l3);
    // d = 4l .. 4l+3 (same chunk, same kslot, j = d&7 in {0,4})
    const int d = l * 4;
    const size_t off = (size_t)(d >> 5) * 8192          // chunk (16 KB in ushorts)
                     + (size_t)(k >> 4) * 512           // ctile (1 KB)
                     + (size_t)((((d >> 3) & 3) << 4) | (k & 15)) * 8   // lane l'
                     + (d & 7);                         // j
    *(ushort4*)(CHg + off) = make_ushort4(h0,h1,h2,h3);
    *(ushort4*)(CLg + off) = make_ushort4(l0,l1,l2,l3);
    double s = (double)v.x*v.x + (double)v.y*v.y + (double)v.z*v.z + (double)v.w*v.w;
    #pragma unroll
    for (int off2 = 32; off2 >= 1; off2 >>= 1) s += __shfl_xor(s, off2);
    if (l == 0) { c2f[k] = (float)s; c2d[k] = s; }
}

// -------- fused split-bf16 MFMA GEMM + butterfly top-3 + gather-write --------
__global__ __launch_bounds__(256, 2) void score_kernel(
    const float* __restrict__ X, const unsigned short* __restrict__ CHg,
    const unsigned short* __restrict__ CLg, const float* __restrict__ C,
    const float* __restrict__ c2f, unsigned* __restrict__ counter,
    unsigned* __restrict__ list, unsigned cap, float* __restrict__ out) {

    // LDS (ushort units), 40960 ushorts = 80 KB exactly => 2 blocks/CU.
    //   Xbuf[b] = SH + b*4096  : XH[4 tiles][512] then XL (2048+2048)
    //   Cbuf[b] = SH + 8192 + b*16384 : CH[16][512] then CL (8192+8192)
    // Each tile is one MFMA operand set in frag order:
    //   tile[l*8 + j] = elem(row/col = tile*16 + (l&15), k = (l>>4)*8 + j)
    // so every wave frag read / DMA write is a contiguous 1 KiB (conflict-free).
    __shared__ __align__(16) unsigned short SH[40960];

    const int t = threadIdx.x;
    const int rowBase = blockIdx.x * 64;

    const int lane = t & 63, w = t >> 6;
    const int lane16 = t & 15, quad = (t >> 4) & 3;

    // c2 for the epilogue: 4 regs, loaded early (L2-hot, block-invariant)
    float cc2[4];
    #pragma unroll
    for (int c = 0; c < 4; ++c) cc2[c] = c2f[w * 64 + c * 16 + lane16];

    f32x4 acc[4][4];
    #pragma unroll
    for (int r = 0; r < 4; ++r)
        #pragma unroll
        for (int c = 0; c < 4; ++c) acc[r][c] = (f32x4)0.f;

    // X staging role: row xr, k-slot xs; frag position l' = xs*16 + (xr&15)
    // of tile xr>>4 => per-wave writes cover a contiguous 1 KiB.
    const int xr = t >> 2, xs = t & 3;
    const float* xbase = X + (size_t)(rowBase + xr) * 256 + xs * 8;
    const int xoff = (xr >> 4) * 512 + ((xs << 4) | (xr & 15)) * 8;

    // C DMA role: wave w pulls ctiles w*4..w*4+3 (hi+lo), 1 KiB per instr.
    const int clb = (w * 4) * 512 + lane * 8;
    const size_t cgb = (size_t)(w * 4) * 512 + (size_t)lane * 8;

    float4 xa = ((const float4*)xbase)[0];      // chunk 0
    float4 xb = ((const float4*)xbase)[1];

    // ---- prologue: stage chunk 0 into buf 0; prefetch X chunk 1 ----
    {
        unsigned short* CH2 = SH + 8192;
        #pragma unroll
        for (int s2 = 0; s2 < 4; ++s2) {
            gload16(CHg + cgb + s2 * 512, CH2 + clb + s2 * 512);
            gload16(CLg + cgb + s2 * 512, CH2 + 8192 + clb + s2 * 512);
        }
        union { u16x8 v; unsigned short s[8]; } hu, lu;
        float xv[8] = {xa.x, xa.y, xa.z, xa.w, xb.x, xb.y, xb.z, xb.w};
        #pragma unroll
        for (int q = 0; q < 8; ++q) split_f32(xv[q], hu.s[q], lu.s[q]);
        *(u16x8*)(SH + xoff) = hu.v;
        *(u16x8*)(SH + 2048 + xoff) = lu.v;
        xa = ((const float4*)(xbase + 32))[0];  // chunk 1
        xb = ((const float4*)(xbase + 32))[1];
    }
    __syncthreads();   // vmcnt(0)+lgkmcnt(0): chunk-0 stage visible

    int cur = 0;
    for (int chunk = 0; chunk < 8; ++chunk, cur ^= 1) {
        // ---- stage chunk+1 into buf cur^1 (issued BEFORE the MFMA cluster) ----
        if (chunk < 7) {
            unsigned short* CH2n = SH + 8192 + (cur ^ 1) * 16384;
            const size_t gb = (size_t)(chunk + 1) * 8192 + cgb;
            #pragma unroll
            for (int s2 = 0; s2 < 4; ++s2) {
                gload16(CHg + gb + s2 * 512, CH2n + clb + s2 * 512);
                gload16(CLg + gb + s2 * 512, CH2n + 8192 + clb + s2 * 512);
            }
            union { u16x8 v; unsigned short s[8]; } hu, lu;
            float xv[8] = {xa.x, xa.y, xa.z, xa.w, xb.x, xb.y, xb.z, xb.w};
            #pragma unroll
            for (int q = 0; q < 8; ++q) split_f32(xv[q], hu.s[q], lu.s[q]);
            unsigned short* XH2n = SH + (cur ^ 1) * 4096;
            *(u16x8*)(XH2n + xoff) = hu.v;
            *(u16x8*)(XH2n + 2048 + xoff) = lu.v;
            if (chunk < 6) {                    // prefetch X chunk+2 into regs
                const float* nx = xbase + (chunk + 2) * 32;
                xa = ((const float4*)nx)[0];
                xb = ((const float4*)nx)[1];
            }
        }

        // ---- compute from buf cur: frag reads are contiguous 1 KiB/wave ----
        unsigned short* XH2 = SH + cur * 4096;
        unsigned short* XL2 = XH2 + 2048;
        unsigned short* CH2 = SH + 8192 + cur * 16384;
        unsigned short* CL2 = CH2 + 8192;

        bf16x8 ah[4], al[4];
        #pragma unroll
        for (int r = 0; r < 4; ++r) {
            ah[r] = *(const bf16x8*)(XH2 + r * 512 + lane * 8);
            al[r] = *(const bf16x8*)(XL2 + r * 512 + lane * 8);
        }
        #pragma unroll
        for (int c = 0; c < 4; ++c) {
            const int cb = (w * 4 + c) * 512 + lane * 8;
            bf16x8 bh = *(const bf16x8*)(CH2 + cb);
            bf16x8 bl = *(const bf16x8*)(CL2 + cb);
            #pragma unroll
            for (int r = 0; r < 4; ++r) {
                acc[r][c] = __builtin_amdgcn_mfma_f32_16x16x32_bf16(ah[r], bh, acc[r][c], 0, 0, 0);
                acc[r][c] = __builtin_amdgcn_mfma_f32_16x16x32_bf16(al[r], bh, acc[r][c], 0, 0, 0);
                acc[r][c] = __builtin_amdgcn_mfma_f32_16x16x32_bf16(ah[r], bl, acc[r][c], 0, 0, 0);
            }
        }
        __syncthreads();   // one vmcnt(0)+barrier per chunk, AFTER the MFMAs
    }

    // ---- epilogue: stage dead; overlay WKEY + bestIdx into SH ----
    unsigned* WKEY = (unsigned*)SH;          // [row][13] u32, 3328 B
    int* bestIdx = (int*)(SH + 2048);        // byte offset 4096, 256 B

    #pragma unroll
    for (int r = 0; r < 4; ++r) {
        #pragma unroll
        for (int i = 0; i < 4; ++i) {
            unsigned k1 = 0, k2 = 0, k3 = 0;   // all real keys > 0
            #pragma unroll
            for (int c = 0; c < 4; ++c) {
                float s = cc2[c] - 2.f * acc[r][c][i];
                unsigned cent = (unsigned)(w * 64 + c * 16 + lane16);
                unsigned key = (f32_key(s) & 0xFFFFFF00u) | (255u - cent);
                ins3(k1, k2, k3, key);
            }
            // butterfly over the 16-lane group; partners hold disjoint columns
            #pragma unroll
            for (int m = 1; m <= 8; m <<= 1) {
                unsigned o1 = __shfl_xor(k1, m);
                unsigned o2 = __shfl_xor(k2, m);
                unsigned o3 = __shfl_xor(k3, m);
                ins3(k1, k2, k3, o1); ins3(k1, k2, k3, o2); ins3(k1, k2, k3, o3);
            }
            if (lane16 == 0) {
                const int row = r * 16 + quad * 4 + i;
                unsigned* p = WKEY + row * 13 + w * 3;   // stride 13: coprime to 32
                p[0] = k1; p[1] = k2; p[2] = k3;
            }
        }
    }
    __syncthreads();

    // final: one thread per row merges 4 waves' triples (stride-13 => no conflict)
    if (t < 64) {
        unsigned k1 = 0, k2 = 0, k3 = 0;
        #pragma unroll
        for (int w2 = 0; w2 < 4; ++w2) {
            const unsigned* p = WKEY + t * 13 + w2 * 3;
            ins3(k1, k2, k3, p[0]); ins3(k1, k2, k3, p[1]); ins3(k1, k2, k3, p[2]);
        }
        bestIdx[t] = 255 - (int)(k2 & 0xFFu);
        float s1 = key_to_float(k1), s2 = key_to_float(k2), s3 = key_to_float(k3);
        if (s1 - s2 < EPS || s2 - s3 < EPS) {
            unsigned p = atomicAdd(counter, 1u);
            if (p < cap) list[p] = (unsigned)(rowBase + t);
        }
    }
    __syncthreads();

    // gather-write: 4 threads per row, 16 float4 each
    {
        const int r = t >> 2, q0 = t & 3;
        const int c = bestIdx[r];
        const float4* src = (const float4*)(C + (size_t)c * 256);
        float4* dst = (float4*)(out + (size_t)(rowBase + r) * 256);
        #pragma unroll
        for (int q = 0; q < 16; ++q) dst[q0 + 4 * q] = src[q0 + 4 * q];
    }
}

// -------- exact f64 re-rank of flagged rows --------
__global__ __launch_bounds__(256) void refine_kernel(
    const float* __restrict__ X, const float* __restrict__ C,
    const double* __restrict__ c2d, const unsigned* __restrict__ counter,
    const unsigned* __restrict__ list, unsigned cap, float* __restrict__ out) {

    __shared__ float xs[256];
    __shared__ double sh[256];
    __shared__ int b2s;
    unsigned count = *counter;
    if (count > cap) count = cap;
    const int k = threadIdx.x;

    for (unsigned idx = blockIdx.x; idx < count; idx += gridDim.x) {
        const unsigned row = list[idx];
        xs[k] = X[(size_t)row * 256 + k];
        __syncthreads();
        const float4* cp = (const float4*)(C + (size_t)k * 256);
        double a = 0.0;
        #pragma unroll 4
        for (int j = 0; j < 64; ++j) {
            float4 c4 = cp[j];
            a += (double)c4.x * xs[4 * j + 0] + (double)c4.y * xs[4 * j + 1]
               + (double)c4.z * xs[4 * j + 2] + (double)c4.w * xs[4 * j + 3];
        }
        sh[k] = c2d[k] - 2.0 * a;
        __syncthreads();
        if (k == 0) {
            double b1 = -1e300, b2 = -1e300;
            int i1 = 0, i2 = 0;
            for (int q = 0; q < 256; ++q) {
                double s = sh[q];
                if (s > b1)      { b2 = b1; i2 = i1; b1 = s; i1 = q; }
                else if (s > b2) { b2 = s;  i2 = q; }
            }
            b2s = i2;
        }
        __syncthreads();
        const int csel = b2s;
        if (k < 64) {
            const float4* src = (const float4*)(C + (size_t)csel * 256);
            float4* dst = (float4*)(out + (size_t)row * 256);
            dst[k] = src[k];
        }
        __syncthreads();   // xs/sh reused next iteration
    }
}

extern "C" void kernel_launch(void* const* d_in, const int* in_sizes, int n_in,
                              void* d_out, int out_size, void* d_ws, size_t ws_size,
                              hipStream_t stream) {
    const float* X = (const float*)d_in[0];
    const float* C = (const float*)d_in[1];
    float* out = (float*)d_out;
    const int N = in_sizes[0] / 256;

    // ws: [0,64) counter | [64) c2f(1KB) | [2048) c2d(2KB) | [4096) CH(128KB)
    //     | [135168) CL(128KB) | [266240) flag list
    unsigned* counter = (unsigned*)d_ws;
    float* c2f = (float*)((char*)d_ws + 64);
    double* c2d = (double*)((char*)d_ws + 2048);
    unsigned short* CHg = (unsigned short*)((char*)d_ws + 4096);
    unsigned short* CLg = (unsigned short*)((char*)d_ws + 135168);
    unsigned* list = (unsigned*)((char*)d_ws + 266240);
    unsigned cap = 0;
    if (ws_size > 266240) {
        size_t c = (ws_size - 266240) / 4;
        cap = (unsigned)(c < (size_t)CAP_MAX ? c : (size_t)CAP_MAX);
    }

    hipMemsetAsync(d_ws, 0, 64, stream);
    cvt_kernel<<<256, 64, 0, stream>>>(C, c2f, c2d, CHg, CLg);
    score_kernel<<<N / 64, 256, 0, stream>>>(X, CHg, CLg, C, c2f, counter, list, cap, out);
    refine_kernel<<<1024, 256, 0, stream>>>(X, C, c2d, counter, list, cap, out);
}

// Round 3
// 1078.608 us; speedup vs baseline: 1.1152x; 1.1152x over previous
//
#include <hip/hip_runtime.h>
#include <hip/hip_bf16.h>

// NegSamplerMiniBatch: out[n] = centroids[ idx of 2nd-largest distance(x_n,c_k) ]
// N=262144, D=256, K=256, f32.
//
// Rank key: s_k = |c_k|^2 - 2 x.c_k (monotone in distance). Dot via split-bf16
// MFMA: x = xh + xl, c = ch + cl (truncation splits); dot ~= xh.ch + xl.ch +
// xh.cl, f32 accumulate. Rows with top-3 gap < EPS=0.02 exactly re-ranked in
// f64 by refine_kernel.
//
// v3: register-staged C (NO global_load_lds: DMA forces vmcnt(0) drain at every
// barrier, serializing the block on HBM latency — rounds 1/2 regression).
// C global buffer is in chunk-major MFMA-fragment order, addressed so every
// global load AND every ds_write is a contiguous 1 KiB per wave instruction
// (coalesced / conflict-free). Single-buffer 40 KB LDS -> 3 blocks/CU.
// Loads for the next chunk are issued at the top of the MFMA phase; X is
// prefetched 2 chunks ahead via statically ping-ponged registers.

typedef __attribute__((ext_vector_type(8))) __bf16 bf16x8;
typedef __attribute__((ext_vector_type(4))) float f32x4;
typedef __attribute__((ext_vector_type(8))) unsigned short u16x8;

#define EPS 0.02f
#define CAP_MAX 65536

__device__ __forceinline__ void split_f32(float v, unsigned short& hi, unsigned short& lo) {
    unsigned u = __float_as_uint(v);
    hi = (unsigned short)(u >> 16);                      // truncate to bf16
    float hif = __uint_as_float(u & 0xFFFF0000u);
    float lov = v - hif;                                 // exact residual
    lo = (unsigned short)(__float_as_uint(lov) >> 16);
}

__device__ __forceinline__ unsigned f32_key(float s) {   // order-preserving u32
    unsigned u = __float_as_uint(s);
    return u ^ ((unsigned)((int)u >> 31) | 0x80000000u);
}
__device__ __forceinline__ float key_to_float(unsigned key) {
    unsigned k = key & 0xFFFFFF00u;
    unsigned u = (k & 0x80000000u) ? (k ^ 0x80000000u) : ~k;
    return __uint_as_float(u);
}

__device__ __forceinline__ void ins3(unsigned& k1, unsigned& k2, unsigned& k3, unsigned v) {
    if (v > k1)      { k3 = k2; k2 = k1; k1 = v; }
    else if (v > k2) { k3 = k2; k2 = v; }
    else if (v > k3) { k3 = v; }
}

// -------- one-time: C -> bf16 hi/lo in frag-order layout, plus c2 --------
__global__ __launch_bounds__(64) void cvt_kernel(const float* __restrict__ C,
    float* __restrict__ c2f, double* __restrict__ c2d,
    unsigned short* __restrict__ CHg, unsigned short* __restrict__ CLg) {
    const int k = blockIdx.x, l = threadIdx.x;
    float4 v = ((const float4*)(C + (size_t)k * 256))[l];
    unsigned short h0,h1,h2,h3, l0,l1,l2,l3;
    split_f32(v.x,h0,l0); split_f32(v.y,h1,l1); split_f32(v.z,h2,l2); split_f32(v.w,h3,l3);
    // d = 4l .. 4l+3 (same chunk, same kslot, j = d&7 in {0,4})
    const int d = l * 4;
    const size_t off = (size_t)(d >> 5) * 8192          // chunk (16 KB in ushorts)
                     + (size_t)(k >> 4) * 512           // ctile (1 KB)
                     + (size_t)((((d >> 3) & 3) << 4) | (k & 15)) * 8   // lane l'
                     + (d & 7);                         // j
    *(ushort4*)(CHg + off) = make_ushort4(h0,h1,h2,h3);
    *(ushort4*)(CLg + off) = make_ushort4(l0,l1,l2,l3);
    double s = (double)v.x*v.x + (double)v.y*v.y + (double)v.z*v.z + (double)v.w*v.w;
    #pragma unroll
    for (int off2 = 32; off2 >= 1; off2 >>= 1) s += __shfl_xor(s, off2);
    if (l == 0) { c2f[k] = (float)s; c2d[k] = s; }
}

// -------- fused split-bf16 MFMA GEMM + butterfly top-3 + gather-write --------
__global__ __launch_bounds__(256, 3) void score_kernel(
    const float* __restrict__ X, const unsigned short* __restrict__ CHg,
    const unsigned short* __restrict__ CLg, const float* __restrict__ C,
    const float* __restrict__ c2f, unsigned* __restrict__ counter,
    unsigned* __restrict__ list, unsigned cap, float* __restrict__ out) {

    // LDS (ushort units), single buffer, 20480 ushorts = 40 KB -> 3 blocks/CU.
    //   XH[4 tiles][512] | XL | CH[16 tiles][512] | CL
    // tile[l*8 + j] = elem(row/col = tile*16 + (l&15), k = (l>>4)*8 + j):
    // every wave frag read / stage write is a contiguous 1 KiB (conflict-free).
    __shared__ __align__(16) unsigned short SH[20480];
    unsigned short* XH2 = SH;           // 2048
    unsigned short* XL2 = SH + 2048;    // 2048
    unsigned short* CH2 = SH + 4096;    // 8192
    unsigned short* CL2 = SH + 12288;   // 8192

    const int t = threadIdx.x;
    const int rowBase = blockIdx.x * 64;
    const int lane = t & 63, w = t >> 6;
    const int lane16 = t & 15, quad = (t >> 4) & 3;

    // c2 for the epilogue: 4 regs (L2-hot, 1 KB shared by all blocks)
    float cc2[4];
    #pragma unroll
    for (int c = 0; c < 4; ++c) cc2[c] = c2f[w * 64 + c * 16 + lane16];

    f32x4 acc[4][4];
    #pragma unroll
    for (int r = 0; r < 4; ++r)
        #pragma unroll
        for (int c = 0; c < 4; ++c) acc[r][c] = (f32x4)0.f;

    // X staging role: row xr, k-slot xs; frag pos l' = xs*16 + (xr&15) of tile
    // xr>>4 => per-wave writes are a contiguous 1 KiB.
    const int xr = t >> 2, xs = t & 3;
    const float* xbase = X + (size_t)(rowBase + xr) * 256 + xs * 8;
    const int xoff = (xr >> 4) * 512 + ((xs << 4) | (xr & 15)) * 8;

    // C staging role: instruction j covers frag-tile (w*4+j); lane at +lane*16B.
    // Global frag-order layout == LDS layout => same offset both sides.
    const int cofs = w * 2048 + lane * 8;

    // ---- preload: C chunk 0; X chunks 0 (even regs) and 1 (odd regs) ----
    u16x8 chA, chB, chC, chD, clA, clB, clC, clD;
    {
        const u16x8* gh = (const u16x8*)(CHg + cofs);
        chA = gh[0]; chB = gh[64]; chC = gh[128]; chD = gh[192];
        const u16x8* gl2 = (const u16x8*)(CLg + cofs);
        clA = gl2[0]; clB = gl2[64]; clC = gl2[128]; clD = gl2[192];
    }
    float4 xa0 = ((const float4*)xbase)[0];        // even chunks
    float4 xb0 = ((const float4*)xbase)[1];
    float4 xa1 = ((const float4*)(xbase + 32))[0]; // odd chunks
    float4 xb1 = ((const float4*)(xbase + 32))[1];

    // one chunk: write phase | barrier | issue next loads | MFMA phase | barrier
    auto chunk_body = [&](int chunk, float4& xa_, float4& xb_) {
        // ---- write phase (LDS free: all waves past previous MFMA) ----
        union { u16x8 v; unsigned short s[8]; } hu, lu;
        {
            float xv[8] = {xa_.x, xa_.y, xa_.z, xa_.w, xb_.x, xb_.y, xb_.z, xb_.w};
            #pragma unroll
            for (int q = 0; q < 8; ++q) split_f32(xv[q], hu.s[q], lu.s[q]);
        }
        *(u16x8*)(XH2 + xoff) = hu.v;
        *(u16x8*)(XL2 + xoff) = lu.v;
        *(u16x8*)(CH2 + cofs)        = chA;
        *(u16x8*)(CH2 + cofs + 512)  = chB;
        *(u16x8*)(CH2 + cofs + 1024) = chC;
        *(u16x8*)(CH2 + cofs + 1536) = chD;
        *(u16x8*)(CL2 + cofs)        = clA;
        *(u16x8*)(CL2 + cofs + 512)  = clB;
        *(u16x8*)(CL2 + cofs + 1024) = clC;
        *(u16x8*)(CL2 + cofs + 1536) = clD;
        __syncthreads();   // LDS ready (lgkm only — no LDS-DMA in flight)

        // ---- issue next-chunk loads: covered by the MFMA cluster below ----
        if (chunk < 7) {
            const u16x8* gh = (const u16x8*)(CHg + (chunk + 1) * 8192 + cofs);
            chA = gh[0]; chB = gh[64]; chC = gh[128]; chD = gh[192];
            const u16x8* gl2 = (const u16x8*)(CLg + (chunk + 1) * 8192 + cofs);
            clA = gl2[0]; clB = gl2[64]; clC = gl2[128]; clD = gl2[192];
        }
        if (chunk < 6) {   // X two chunks ahead into this parity's regs
            const float* nx = xbase + (chunk + 2) * 32;
            xa_ = ((const float4*)nx)[0];
            xb_ = ((const float4*)nx)[1];
        }

        // ---- MFMA phase: frag reads are contiguous 1 KiB per wave ----
        bf16x8 ah[4], al[4];
        #pragma unroll
        for (int r = 0; r < 4; ++r) {
            ah[r] = *(const bf16x8*)(XH2 + r * 512 + lane * 8);
            al[r] = *(const bf16x8*)(XL2 + r * 512 + lane * 8);
        }
        #pragma unroll
        for (int c = 0; c < 4; ++c) {
            const int cb = (w * 4 + c) * 512 + lane * 8;
            bf16x8 bh = *(const bf16x8*)(CH2 + cb);
            bf16x8 bl = *(const bf16x8*)(CL2 + cb);
            #pragma unroll
            for (int r = 0; r < 4; ++r) {
                acc[r][c] = __builtin_amdgcn_mfma_f32_16x16x32_bf16(ah[r], bh, acc[r][c], 0, 0, 0);
                acc[r][c] = __builtin_amdgcn_mfma_f32_16x16x32_bf16(al[r], bh, acc[r][c], 0, 0, 0);
                acc[r][c] = __builtin_amdgcn_mfma_f32_16x16x32_bf16(ah[r], bl, acc[r][c], 0, 0, 0);
            }
        }
        __syncthreads();   // all waves done reading; next write phase may begin
    };

    #pragma unroll
    for (int cc = 0; cc < 4; ++cc) {       // 2x-unrolled: static reg ping-pong
        chunk_body(cc * 2,     xa0, xb0);
        chunk_body(cc * 2 + 1, xa1, xb1);
    }

    // ---- epilogue: stage dead; overlay WKEY + bestIdx into SH ----
    unsigned* WKEY = (unsigned*)SH;          // [row][13] u32, 3328 B
    int* bestIdx = (int*)(SH + 2048);        // byte offset 4096, 256 B

    #pragma unroll
    for (int r = 0; r < 4; ++r) {
        #pragma unroll
        for (int i = 0; i < 4; ++i) {
            unsigned k1 = 0, k2 = 0, k3 = 0;   // all real keys > 0
            #pragma unroll
            for (int c = 0; c < 4; ++c) {
                float s = cc2[c] - 2.f * acc[r][c][i];
                unsigned cent = (unsigned)(w * 64 + c * 16 + lane16);
                unsigned key = (f32_key(s) & 0xFFFFFF00u) | (255u - cent);
                ins3(k1, k2, k3, key);
            }
            // butterfly over the 16-lane group; partners hold disjoint columns
            #pragma unroll
            for (int m = 1; m <= 8; m <<= 1) {
                unsigned o1 = __shfl_xor(k1, m);
                unsigned o2 = __shfl_xor(k2, m);
                unsigned o3 = __shfl_xor(k3, m);
                ins3(k1, k2, k3, o1); ins3(k1, k2, k3, o2); ins3(k1, k2, k3, o3);
            }
            if (lane16 == 0) {
                const int row = r * 16 + quad * 4 + i;
                unsigned* p = WKEY + row * 13 + w * 3;   // stride 13: coprime to 32
                p[0] = k1; p[1] = k2; p[2] = k3;
            }
        }
    }
    __syncthreads();

    // final: one thread per row merges 4 waves' triples (stride-13 => no conflict)
    if (t < 64) {
        unsigned k1 = 0, k2 = 0, k3 = 0;
        #pragma unroll
        for (int w2 = 0; w2 < 4; ++w2) {
            const unsigned* p = WKEY + t * 13 + w2 * 3;
            ins3(k1, k2, k3, p[0]); ins3(k1, k2, k3, p[1]); ins3(k1, k2, k3, p[2]);
        }
        bestIdx[t] = 255 - (int)(k2 & 0xFFu);
        float s1 = key_to_float(k1), s2 = key_to_float(k2), s3 = key_to_float(k3);
        if (s1 - s2 < EPS || s2 - s3 < EPS) {
            unsigned p = atomicAdd(counter, 1u);
            if (p < cap) list[p] = (unsigned)(rowBase + t);
        }
    }
    __syncthreads();

    // gather-write: 4 threads per row, 16 float4 each
    {
        const int r = t >> 2, q0 = t & 3;
        const int c = bestIdx[r];
        const float4* src = (const float4*)(C + (size_t)c * 256);
        float4* dst = (float4*)(out + (size_t)(rowBase + r) * 256);
        #pragma unroll
        for (int q = 0; q < 16; ++q) dst[q0 + 4 * q] = src[q0 + 4 * q];
    }
}

// -------- exact f64 re-rank of flagged rows --------
__global__ __launch_bounds__(256) void refine_kernel(
    const float* __restrict__ X, const float* __restrict__ C,
    const double* __restrict__ c2d, const unsigned* __restrict__ counter,
    const unsigned* __restrict__ list, unsigned cap, float* __restrict__ out) {

    __shared__ float xs[256];
    __shared__ double sh[256];
    __shared__ int b2s;
    unsigned count = *counter;
    if (count > cap) count = cap;
    const int k = threadIdx.x;

    for (unsigned idx = blockIdx.x; idx < count; idx += gridDim.x) {
        const unsigned row = list[idx];
        xs[k] = X[(size_t)row * 256 + k];
        __syncthreads();
        const float4* cp = (const float4*)(C + (size_t)k * 256);
        double a = 0.0;
        #pragma unroll 4
        for (int j = 0; j < 64; ++j) {
            float4 c4 = cp[j];
            a += (double)c4.x * xs[4 * j + 0] + (double)c4.y * xs[4 * j + 1]
               + (double)c4.z * xs[4 * j + 2] + (double)c4.w * xs[4 * j + 3];
        }
        sh[k] = c2d[k] - 2.0 * a;
        __syncthreads();
        if (k == 0) {
            double b1 = -1e300, b2 = -1e300;
            int i1 = 0, i2 = 0;
            for (int q = 0; q < 256; ++q) {
                double s = sh[q];
                if (s > b1)      { b2 = b1; i2 = i1; b1 = s; i1 = q; }
                else if (s > b2) { b2 = s;  i2 = q; }
            }
            b2s = i2;
        }
        __syncthreads();
        const int csel = b2s;
        if (k < 64) {
            const float4* src = (const float4*)(C + (size_t)csel * 256);
            float4* dst = (float4*)(out + (size_t)row * 256);
            dst[k] = src[k];
        }
        __syncthreads();   // xs/sh reused next iteration
    }
}

extern "C" void kernel_launch(void* const* d_in, const int* in_sizes, int n_in,
                              void* d_out, int out_size, void* d_ws, size_t ws_size,
                              hipStream_t stream) {
    const float* X = (const float*)d_in[0];
    const float* C = (const float*)d_in[1];
    float* out = (float*)d_out;
    const int N = in_sizes[0] / 256;

    // ws: [0,64) counter | [64) c2f(1KB) | [2048) c2d(2KB) | [4096) CH(128KB)
    //     | [135168) CL(128KB) | [266240) flag list
    unsigned* counter = (unsigned*)d_ws;
    float* c2f = (float*)((char*)d_ws + 64);
    double* c2d = (double*)((char*)d_ws + 2048);
    unsigned short* CHg = (unsigned short*)((char*)d_ws + 4096);
    unsigned short* CLg = (unsigned short*)((char*)d_ws + 135168);
    unsigned* list = (unsigned*)((char*)d_ws + 266240);
    unsigned cap = 0;
    if (ws_size > 266240) {
        size_t c = (ws_size - 266240) / 4;
        cap = (unsigned)(c < (size_t)CAP_MAX ? c : (size_t)CAP_MAX);
    }

    hipMemsetAsync(d_ws, 0, 64, stream);
    cvt_kernel<<<256, 64, 0, stream>>>(C, c2f, c2d, CHg, CLg);
    score_kernel<<<N / 64, 256, 0, stream>>>(X, CHg, CLg, C, c2f, counter, list, cap, out);
    refine_kernel<<<1024, 256, 0, stream>>>(X, C, c2d, counter, list, cap, out);
}